// Round 4
// baseline (491.487 us; speedup 1.0000x reference)
//
#include <hip/hip_runtime.h>
#include <hip/hip_bf16.h>
#include <hip/hip_cooperative_groups.h>

namespace cg = cooperative_groups;

typedef unsigned int u32;
typedef unsigned short u16;
typedef __hip_bfloat16 bf16;

typedef __attribute__((ext_vector_type(8))) short short8;
typedef __attribute__((ext_vector_type(4))) float float4v;

#define CAP 5120  // per-(set,bucket) edge capacity; avg ~4082 (Poisson), +16 sigma

__device__ __forceinline__ float lrelu(float v) { return v > 0.f ? v : 0.2f * v; }

// f32 -> bf16 bits, round-to-nearest-even
__device__ __forceinline__ u16 f2b(float f) {
  u32 x = __float_as_uint(f);
  u32 r = (x + 0x7fffu + ((x >> 16) & 1u)) >> 16;
  return (u16)r;
}
__device__ __forceinline__ float b2fbits(u16 b) {
  return __uint_as_float(((u32)b) << 16);
}
// unpack a dword holding 2 bf16: low half = even feature, high half = odd feature
__device__ __forceinline__ float blo(u32 v) { return __uint_as_float(v << 16); }
__device__ __forceinline__ float bhi(u32 v) { return __uint_as_float(v & 0xffff0000u); }

struct EdgePtrs { const int* e[8]; };

// ---------------- kernel 0: zero bucket counters (graph-capture-safe memset)
__global__ __launch_bounds__(256) void CSGDN_32031866093637_kernel(u32* __restrict__ p,
                                                                   int count) {
  int i = blockIdx.x * 256 + threadIdx.x;
  if (i < count) p[i] = 0;
}

// ---------------- fused prep kernel: bin blocks first, then gemm blocks.
// bin and gemm are data-independent (bin: edges->bbuf/gcnt; gemm: x,W->H,sv,dv),
// so one dispatch lets memory-heavy bin overlap with compute-heavy gemm.

__device__ __forceinline__ void gemm_role(
    u32* smem, int g, const float* __restrict__ x, const float* __restrict__ W,
    const float* __restrict__ a_src, const float* __restrict__ a_dst,
    u16* __restrict__ H, float* __restrict__ sv, float* __restrict__ dv, int n) {
  const int p = g & 3;
  const int rowbase = (g >> 2) * 64;
  const int tid = threadIdx.x, lane = tid & 63, wv = tid >> 6;
  // padded stride 72 elem (144 B = 9*16B): b128-aligned, frag reads 2-way alias only
  short* xl = (short*)smem;          // 64*72 shorts = 9216 B
  short* wl = xl + 64 * 72;          // 64*72 shorts = 9216 B
#pragma unroll
  for (int it = 0; it < 16; it++) {
    int idx = it * 256 + tid;
    int r = idx >> 6, c = idx & 63;
    int gr = rowbase + r; if (gr > n - 1) gr = n - 1;
    xl[r * 72 + c] = (short)f2b(x[(size_t)gr * 64 + c]);
  }
#pragma unroll
  for (int it = 0; it < 16; it++) {
    int idx = it * 256 + tid;
    int k = idx >> 6, nc = idx & 63;
    wl[nc * 72 + k] = (short)f2b(W[p * 4096 + k * 64 + nc]);
  }
  __syncthreads();

  const int q = lane >> 4, c15 = lane & 15;
  const int wrow0 = wv * 16;  // this wave's 16 rows (local)
  short8 af0 = *(const short8*)&xl[(wrow0 + c15) * 72 + 0 * 32 + q * 8];
  short8 af1 = *(const short8*)&xl[(wrow0 + c15) * 72 + 1 * 32 + q * 8];
  float4v acc[4];
#pragma unroll
  for (int nt = 0; nt < 4; nt++) {
    acc[nt] = (float4v){0.f, 0.f, 0.f, 0.f};
    short8 b0 = *(const short8*)&wl[(nt * 16 + c15) * 72 + 0 * 32 + q * 8];
    short8 b1 = *(const short8*)&wl[(nt * 16 + c15) * 72 + 1 * 32 + q * 8];
    acc[nt] = __builtin_amdgcn_mfma_f32_16x16x32_bf16(af0, b0, acc[nt], 0, 0, 0);
    acc[nt] = __builtin_amdgcn_mfma_f32_16x16x32_bf16(af1, b1, acc[nt], 0, 0, 0);
  }
  // D layout: row = q*4 + r, col = nt*16 + c15
  u16* Hb = H + (size_t)p * n * 64;
  float as4[4], ad4[4];
#pragma unroll
  for (int nt = 0; nt < 4; nt++) {
    as4[nt] = a_src[p * 64 + nt * 16 + c15];
    ad4[nt] = a_dst[p * 64 + nt * 16 + c15];
  }
#pragma unroll
  for (int r = 0; r < 4; r++) {
    int row_g = rowbase + wrow0 + q * 4 + r;
    bool ok = row_g < n;
#pragma unroll
    for (int nt = 0; nt < 4; nt++) {
      if (ok) Hb[(size_t)row_g * 64 + nt * 16 + c15] = f2b(acc[nt][r]);
    }
    float ps = 0.f, pd = 0.f;
#pragma unroll
    for (int nt = 0; nt < 4; nt++) {
      ps = fmaf(acc[nt][r], as4[nt], ps);
      pd = fmaf(acc[nt][r], ad4[nt], pd);
    }
#pragma unroll
    for (int o = 1; o < 16; o <<= 1) {
      ps += __shfl_xor(ps, o, 64);
      pd += __shfl_xor(pd, o, 64);
    }
    if (ok && c15 == 0) {
      sv[(size_t)p * n + row_g] = ps;
      dv[(size_t)p * n + row_g] = pd;
    }
  }
}

__device__ __forceinline__ void bin_role(
    u32* smem, int bf, EdgePtrs ep, u32* __restrict__ gcnt, u32* __restrict__ bbuf,
    int E, int nb) {
  int set = bf & 7, chunk = bf >> 3;
  const int* e = ep.e[set];
  u32* hist = smem;            // 256
  u32* gbase = smem + 256;     // 256
  u32* curs = smem + 512;      // 256
  u32* loffs = smem + 768;     // 257
  u32* sorted = smem + 1028;   // 4096
  int tid = threadIdx.x, lane = tid & 63, wv = tid >> 6;
  hist[tid] = 0;
  curs[tid] = 0;
  __syncthreads();
  int start = chunk * 4096;
  u32 pk_r[16];
#pragma unroll
  for (int t = 0; t < 16; t++) {
    int i = start + t * 256 + tid;
    u32 pk = 0xffffffffu;  // sentinel (real pk < 0xC350xxxx since d < n < 65536)
    if (i < E) {
      int s = e[i], d = e[E + i];
      if (s != d) {  // self-edges masked by ref -> weight 0
        pk = ((u32)d << 16) | (u32)s;
        atomicAdd(&hist[d >> 8], 1u);
      }
    }
    pk_r[t] = pk;
  }
  __syncthreads();
  if (hist[tid] > 0) gbase[tid] = atomicAdd(&gcnt[set * nb + tid], hist[tid]);
  if (wv == 0) {
    u32 carry = 0;
    for (int base = 0; base < 256; base += 64) {
      u32 v = hist[base + lane], x = v;
#pragma unroll
      for (int o = 1; o < 64; o <<= 1) { u32 y = __shfl_up(x, o, 64); if (lane >= o) x += y; }
      loffs[base + lane] = carry + x - v;
      carry += __shfl(x, 63, 64);
    }
    if (lane == 0) loffs[256] = carry;
  }
  __syncthreads();
#pragma unroll
  for (int t = 0; t < 16; t++) {
    u32 pk = pk_r[t];
    if (pk != 0xffffffffu) {
      int b = pk >> 24;  // (d << 16) >> 24 == d >> 8
      u32 pos = loffs[b] + atomicAdd(&curs[b], 1u);
      sorted[pos] = pk;
    }
  }
  __syncthreads();
  int cnt = (int)loffs[256];
  for (int j = tid; j < cnt; j += 256) {
    u32 pk = sorted[j];
    int b = pk >> 24;
    u32 gpos = gbase[b] + ((u32)j - loffs[b]);
    if (gpos >= CAP) gpos = CAP - 1;  // statistically impossible; memory safety only
    bbuf[((size_t)(set * nb + b)) * CAP + gpos] = pk;
  }
}

__global__ __launch_bounds__(256) void prep_kernel(
    EdgePtrs ep, u32* __restrict__ gcnt, u32* __restrict__ bbuf, int E, int nb,
    int nbin,
    const float* __restrict__ x, const float* __restrict__ W,
    const float* __restrict__ a_src, const float* __restrict__ a_dst,
    u16* __restrict__ H, float* __restrict__ sv, float* __restrict__ dv, int n) {
  __shared__ __align__(16) u32 smem[5248];  // 21 KB union: bin 20.5 KB / gemm 18.4 KB
  int f = blockIdx.x;
  if (f < nbin) bin_role(smem, f, ep, gcnt, bbuf, E, nb);
  else gemm_role(smem, f - nbin, x, W, a_src, a_dst, H, sv, dv, n);
}

// ---------------- cooperative kernel: part A = per-bucket counting sort -> global
// sorted (src, exp-score) arrays + CSR row pointers; grid.sync(); part B = pure
// gather-aggregate, node-chunked over exactly-resident blocks (no launch tail, no
// LDS residency cost, occupancy ceiling 100%). set = blockIdx&7 keeps XCD affinity
// for the H-panel L2 working set in both parts.
__global__ __launch_bounds__(512, 8) void agg_fused(
    const u32* __restrict__ gcnt, const u32* __restrict__ bbuf,
    const u16* __restrict__ H, const float* __restrict__ sv,
    const float* __restrict__ dv, const float* __restrict__ bias,
    float* __restrict__ out, u16* __restrict__ s_srt, float* __restrict__ pe_srt,
    u32* __restrict__ rs, u32* __restrict__ rc, int n, int nb) {
  // input set order: tp_a,tp_b,tn_a,tn_b,dp_a,dp_b,dn_a,dn_b
  // output order:    tp_a,tp_b,dp_a,dp_b,tn_a,tn_b,dn_a,dn_b
  const int omap[8] = {0, 1, 4, 5, 2, 3, 6, 7};
  const int tid = threadIdx.x, lane = tid & 63, wv = tid >> 6;
  __shared__ u16 ss[CAP];        // 10 KB: src ids sorted by dst
  __shared__ float spe[CAP];     // 20 KB: exp-scores sorted by dst
  __shared__ u32 hist[256], offs[257], curs[256];
  __shared__ float dpw[256];

  // ================= part A: sort each (set,bucket), write to global =================
  const int ntask = 8 * nb;
  for (int task = blockIdx.x; task < ntask; task += gridDim.x) {
    // gridDim.x is a multiple of 8 -> set stays fixed per block across iterations
    int set = task & 7, b = task >> 3, p = set >> 1;
    int node0 = b << 8;
    int nn = min(256, n - node0);
    const float* sp = sv + (size_t)p * n;
    const float* dp = dv + (size_t)p * n;
    for (int i = tid; i < 256; i += 512) { hist[i] = 0; curs[i] = 0; }
    for (int i = tid; i < nn; i += 512) dpw[i] = dp[node0 + i];
    __syncthreads();
    int cnt = (int)gcnt[set * nb + b];
    if (cnt > CAP) cnt = CAP;
    size_t ebase = (size_t)(set * nb + b) * CAP;
    const u32* eb = bbuf + ebase;
    // phase 1: load packed edges once, histogram + exp-scores
    u32 pk_r[10];
    float pe_r[10];
#pragma unroll
    for (int t = 0; t < 10; t++) {
      int j = t * 512 + tid;
      u32 pk = 0;
      float pe = 0.f;
      if (j < cnt) {
        pk = eb[j];
        int s = pk & 0xffff, dl = (pk >> 16) & 255;
        atomicAdd(&hist[dl], 1u);
        pe = __expf(lrelu(sp[s] + dpw[dl]));
      }
      pk_r[t] = pk;
      pe_r[t] = pe;
    }
    __syncthreads();
    // phase 2: exclusive prefix scan (wave 0)
    if (wv == 0) {
      u32 carry = 0;
      for (int base = 0; base < 256; base += 64) {
        u32 v = hist[base + lane];
        u32 x = v;
#pragma unroll
        for (int o = 1; o < 64; o <<= 1) { u32 y = __shfl_up(x, o, 64); if (lane >= o) x += y; }
        offs[base + lane] = carry + x - v;
        carry += __shfl(x, 63, 64);
      }
      if (lane == 0) offs[256] = carry;
    }
    __syncthreads();
    // phase 3: scatter into sorted order (LDS)
#pragma unroll
    for (int t = 0; t < 10; t++) {
      int j = t * 512 + tid;
      if (j < cnt) {
        u32 pk = pk_r[t];
        int dl = (pk >> 16) & 255;
        u32 pos = offs[dl] + atomicAdd(&curs[dl], 1u);
        ss[pos] = (u16)(pk & 0xffff);
        spe[pos] = pe_r[t];
      }
    }
    __syncthreads();
    // writeback: sorted arrays (coalesced) + CSR row pointers
    for (int j = tid; j < cnt; j += 512) {
      s_srt[ebase + j] = ss[j];
      pe_srt[ebase + j] = spe[j];
    }
    for (int i = tid; i < nn; i += 512) {
      rs[(size_t)set * n + node0 + i] = (u32)ebase + offs[i];
      rc[(size_t)set * n + node0 + i] = offs[i + 1] - offs[i];
    }
    __syncthreads();  // protect ss/spe/offs before next task reuses them
  }

  __threadfence();
  cg::this_grid().sync();

  // ================= part B: gather-aggregate, node-chunked =================
  {
    int set = blockIdx.x & 7, p = set >> 1;
    int bps = gridDim.x >> 3;            // blocks per set
    int blk = blockIdx.x >> 3;
    int nch = (n + bps - 1) / bps;       // nodes per block (contiguous chunk)
    int lo = blk * nch, hi = min(n, lo + nch);
    const int g = lane >> 3, sub = lane & 7;
    const u16* Hp = H + (size_t)p * n * 64;
    const float* sp = sv + (size_t)p * n;
    const float* dp = dv + (size_t)p * n;
    const u32* rsp = rs + (size_t)set * n;
    const u32* rcp = rc + (size_t)set * n;
    float4v bv0 = *(const float4v*)&bias[p * 64 + sub * 8];
    float4v bv1 = *(const float4v*)&bias[p * 64 + sub * 8 + 4];
    float* op = out + (size_t)omap[set] * n * 64;
    for (int base = lo; base < hi; base += 64) {
      int node = base + wv * 8 + g;      // wave covers 8 consecutive nodes
      bool valid = node < hi;
      int nd = valid ? node : lo;        // safe address for masked-off groups
      int beg = (int)rsp[nd];
      int cntg = valid ? (int)rcp[nd] : 0;
      // self-loop seeds the accumulators (loads overlap the edge loop issue)
      float pself = valid ? __expf(lrelu(sp[nd] + dp[nd])) : 0.f;
      uint4 hs = *(const uint4*)(Hp + ((size_t)nd << 6) + (sub << 3));
      float den = pself;
      float a0 = pself * blo(hs.x), a1 = pself * bhi(hs.x);
      float a2 = pself * blo(hs.y), a3 = pself * bhi(hs.y);
      float a4 = pself * blo(hs.z), a5 = pself * bhi(hs.z);
      float a6 = pself * blo(hs.w), a7 = pself * bhi(hs.w);
      // 4 edges per iteration: 4 independent H-row gathers in flight.
      // Per-group trip count; inactive groups are exec-masked (no wave-max needed).
      for (int t = 0; t < cntg; t += 4) {
        bool c1 = t + 1 < cntg, c2 = t + 2 < cntg, c3 = t + 3 < cntg;
        int j0 = beg + t;
        int j1 = c1 ? j0 + 1 : j0;
        int j2 = c2 ? j0 + 2 : j0;
        int j3 = c3 ? j0 + 3 : j0;
        float pe0 = pe_srt[j0];
        float pe1 = pe_srt[j1]; if (!c1) pe1 = 0.f;
        float pe2 = pe_srt[j2]; if (!c2) pe2 = 0.f;
        float pe3 = pe_srt[j3]; if (!c3) pe3 = 0.f;
        int s0 = s_srt[j0], s1 = s_srt[j1], s2 = s_srt[j2], s3 = s_srt[j3];
        uint4 hv0 = *(const uint4*)(Hp + ((size_t)s0 << 6) + (sub << 3));
        uint4 hv1 = *(const uint4*)(Hp + ((size_t)s1 << 6) + (sub << 3));
        uint4 hv2 = *(const uint4*)(Hp + ((size_t)s2 << 6) + (sub << 3));
        uint4 hv3 = *(const uint4*)(Hp + ((size_t)s3 << 6) + (sub << 3));
        a0 = fmaf(pe0, blo(hv0.x), a0); a1 = fmaf(pe0, bhi(hv0.x), a1);
        a2 = fmaf(pe0, blo(hv0.y), a2); a3 = fmaf(pe0, bhi(hv0.y), a3);
        a4 = fmaf(pe0, blo(hv0.z), a4); a5 = fmaf(pe0, bhi(hv0.z), a5);
        a6 = fmaf(pe0, blo(hv0.w), a6); a7 = fmaf(pe0, bhi(hv0.w), a7);
        a0 = fmaf(pe1, blo(hv1.x), a0); a1 = fmaf(pe1, bhi(hv1.x), a1);
        a2 = fmaf(pe1, blo(hv1.y), a2); a3 = fmaf(pe1, bhi(hv1.y), a3);
        a4 = fmaf(pe1, blo(hv1.z), a4); a5 = fmaf(pe1, bhi(hv1.z), a5);
        a6 = fmaf(pe1, blo(hv1.w), a6); a7 = fmaf(pe1, bhi(hv1.w), a7);
        a0 = fmaf(pe2, blo(hv2.x), a0); a1 = fmaf(pe2, bhi(hv2.x), a1);
        a2 = fmaf(pe2, blo(hv2.y), a2); a3 = fmaf(pe2, bhi(hv2.y), a3);
        a4 = fmaf(pe2, blo(hv2.z), a4); a5 = fmaf(pe2, bhi(hv2.z), a5);
        a6 = fmaf(pe2, blo(hv2.w), a6); a7 = fmaf(pe2, bhi(hv2.w), a7);
        a0 = fmaf(pe3, blo(hv3.x), a0); a1 = fmaf(pe3, bhi(hv3.x), a1);
        a2 = fmaf(pe3, blo(hv3.y), a2); a3 = fmaf(pe3, bhi(hv3.y), a3);
        a4 = fmaf(pe3, blo(hv3.z), a4); a5 = fmaf(pe3, bhi(hv3.z), a5);
        a6 = fmaf(pe3, blo(hv3.w), a6); a7 = fmaf(pe3, bhi(hv3.w), a7);
        den += (pe0 + pe1) + (pe2 + pe3);
      }
      if (valid) {  // all 64 lanes store: 8 nodes x 256B contiguous per wave
        float rd = 1.f / den;
        float4v o0 = {fmaxf(fmaf(a0, rd, bv0.x), 0.f), fmaxf(fmaf(a1, rd, bv0.y), 0.f),
                      fmaxf(fmaf(a2, rd, bv0.z), 0.f), fmaxf(fmaf(a3, rd, bv0.w), 0.f)};
        float4v o1 = {fmaxf(fmaf(a4, rd, bv1.x), 0.f), fmaxf(fmaf(a5, rd, bv1.y), 0.f),
                      fmaxf(fmaf(a6, rd, bv1.z), 0.f), fmaxf(fmaf(a7, rd, bv1.w), 0.f)};
        *(float4v*)&op[((size_t)nd << 6) + (sub << 3)] = o0;
        *(float4v*)&op[((size_t)nd << 6) + (sub << 3) + 4] = o1;
      }
    }
  }
}

extern "C" void kernel_launch(void* const* d_in, const int* in_sizes, int n_in,
                              void* d_out, int out_size, void* d_ws, size_t ws_size,
                              hipStream_t stream) {
  const int E = in_sizes[0] / 2;
  const int n = in_sizes[8] / 64;
  const int nb = (n + 255) >> 8;
  const float* x = (const float*)d_in[8];
  const float* W = (const float*)d_in[9];
  const float* a_src = (const float*)d_in[10];
  const float* a_dst = (const float*)d_in[11];
  const float* bias = (const float*)d_in[12];
  float* out = (float*)d_out;

  char* ws = (char*)d_ws;
  auto alloc = [&](size_t bytes) {
    char* p = ws;
    ws += (bytes + 255) & ~(size_t)255;
    return p;
  };
  u16* H = (u16*)alloc((size_t)4 * n * 64 * 2);
  float* sv = (float*)alloc((size_t)4 * n * 4);
  float* dv = (float*)alloc((size_t)4 * n * 4);
  u32* gcnt = (u32*)alloc((size_t)8 * nb * 4);
  u32* bbuf = (u32*)alloc((size_t)8 * nb * CAP * 4);
  u16* s_srt = (u16*)alloc((size_t)8 * nb * CAP * 2);
  float* pe_srt = (float*)alloc((size_t)8 * nb * CAP * 4);
  u32* rs = (u32*)alloc((size_t)8 * n * 4);
  u32* rc = (u32*)alloc((size_t)8 * n * 4);

  EdgePtrs ep;
  for (int i = 0; i < 8; i++) ep.e[i] = (const int*)d_in[i];

  const int ebpb = (E + 4095) / 4096;      // edge chunks per set
  const int nbin = 8 * ebpb;               // bin blocks (first in flat grid)
  const int ngemm = ((n + 63) / 64) * 4;   // gemm blocks

  dim3 b256(256);
  CSGDN_32031866093637_kernel<<<(8 * nb + 255) / 256, b256, 0, stream>>>(gcnt, 8 * nb);
  prep_kernel<<<nbin + ngemm, b256, 0, stream>>>(ep, gcnt, bbuf, E, nb, nbin,
                                                 x, W, a_src, a_dst, H, sv, dv, n);

  // cooperative launch sized to exact residency (expected 4 blocks/CU * 256 CU = 1024)
  int maxb = 0;
  hipOccupancyMaxActiveBlocksPerMultiprocessor(&maxb, agg_fused, 512, 0);
  if (maxb < 1) maxb = 1;
  int grid = (maxb * 256) & ~7;            // multiple of 8 for set affinity
  if (grid < 8) grid = 8;
  int n_loc = n, nb_loc = nb;
  void* kargs[] = {(void*)&gcnt, (void*)&bbuf, (void*)&H, (void*)&sv, (void*)&dv,
                   (void*)&bias, (void*)&out, (void*)&s_srt, (void*)&pe_srt,
                   (void*)&rs, (void*)&rc, (void*)&n_loc, (void*)&nb_loc};
  hipLaunchCooperativeKernel(agg_fused, dim3(grid), dim3(512), kargs, 0, stream);
}

// Round 5
// 313.516 us; speedup vs baseline: 1.5677x; 1.5677x over previous
//
#include <hip/hip_runtime.h>
#include <hip/hip_bf16.h>

typedef unsigned int u32;
typedef unsigned short u16;
typedef __hip_bfloat16 bf16;

typedef __attribute__((ext_vector_type(8))) short short8;
typedef __attribute__((ext_vector_type(4))) float float4v;

#define CAP 5120  // per-(set,bucket) edge capacity; avg ~4082 (Poisson), +16 sigma

__device__ __forceinline__ float lrelu(float v) { return v > 0.f ? v : 0.2f * v; }

// f32 -> bf16 bits, round-to-nearest-even
__device__ __forceinline__ u16 f2b(float f) {
  u32 x = __float_as_uint(f);
  u32 r = (x + 0x7fffu + ((x >> 16) & 1u)) >> 16;
  return (u16)r;
}
__device__ __forceinline__ float b2fbits(u16 b) {
  return __uint_as_float(((u32)b) << 16);
}
// unpack a dword holding 2 bf16: low half = even feature, high half = odd feature
__device__ __forceinline__ float blo(u32 v) { return __uint_as_float(v << 16); }
__device__ __forceinline__ float bhi(u32 v) { return __uint_as_float(v & 0xffff0000u); }

struct EdgePtrs { const int* e[8]; };

// ---------------- kernel 0: zero bucket counters (graph-capture-safe memset)
__global__ __launch_bounds__(256) void CSGDN_32031866093637_kernel(u32* __restrict__ p,
                                                                   int count) {
  int i = blockIdx.x * 256 + threadIdx.x;
  if (i < count) p[i] = 0;
}

// ---------------- fused prep kernel: bin blocks first, then gemm blocks.
// bin and gemm are data-independent (bin: edges->bbuf/gcnt; gemm: x,W->H,sv,dv),
// so one dispatch lets memory-heavy bin overlap with compute-heavy gemm.

__device__ __forceinline__ void gemm_role(
    u32* smem, int g, const float* __restrict__ x, const float* __restrict__ W,
    const float* __restrict__ a_src, const float* __restrict__ a_dst,
    u16* __restrict__ H, float* __restrict__ sv, float* __restrict__ dv, int n) {
  const int p = g & 3;
  const int rowbase = (g >> 2) * 64;
  const int tid = threadIdx.x, lane = tid & 63, wv = tid >> 6;
  // padded stride 72 elem (144 B = 9*16B): b128-aligned, frag reads 2-way alias only
  short* xl = (short*)smem;          // 64*72 shorts = 9216 B
  short* wl = xl + 64 * 72;          // 64*72 shorts = 9216 B
#pragma unroll
  for (int it = 0; it < 16; it++) {
    int idx = it * 256 + tid;
    int r = idx >> 6, c = idx & 63;
    int gr = rowbase + r; if (gr > n - 1) gr = n - 1;
    xl[r * 72 + c] = (short)f2b(x[(size_t)gr * 64 + c]);
  }
#pragma unroll
  for (int it = 0; it < 16; it++) {
    int idx = it * 256 + tid;
    int k = idx >> 6, nc = idx & 63;
    wl[nc * 72 + k] = (short)f2b(W[p * 4096 + k * 64 + nc]);
  }
  __syncthreads();

  const int q = lane >> 4, c15 = lane & 15;
  const int wrow0 = wv * 16;  // this wave's 16 rows (local)
  short8 af0 = *(const short8*)&xl[(wrow0 + c15) * 72 + 0 * 32 + q * 8];
  short8 af1 = *(const short8*)&xl[(wrow0 + c15) * 72 + 1 * 32 + q * 8];
  float4v acc[4];
#pragma unroll
  for (int nt = 0; nt < 4; nt++) {
    acc[nt] = (float4v){0.f, 0.f, 0.f, 0.f};
    short8 b0 = *(const short8*)&wl[(nt * 16 + c15) * 72 + 0 * 32 + q * 8];
    short8 b1 = *(const short8*)&wl[(nt * 16 + c15) * 72 + 1 * 32 + q * 8];
    acc[nt] = __builtin_amdgcn_mfma_f32_16x16x32_bf16(af0, b0, acc[nt], 0, 0, 0);
    acc[nt] = __builtin_amdgcn_mfma_f32_16x16x32_bf16(af1, b1, acc[nt], 0, 0, 0);
  }
  // D layout: row = q*4 + r, col = nt*16 + c15
  u16* Hb = H + (size_t)p * n * 64;
  float as4[4], ad4[4];
#pragma unroll
  for (int nt = 0; nt < 4; nt++) {
    as4[nt] = a_src[p * 64 + nt * 16 + c15];
    ad4[nt] = a_dst[p * 64 + nt * 16 + c15];
  }
#pragma unroll
  for (int r = 0; r < 4; r++) {
    int row_g = rowbase + wrow0 + q * 4 + r;
    bool ok = row_g < n;
#pragma unroll
    for (int nt = 0; nt < 4; nt++) {
      if (ok) Hb[(size_t)row_g * 64 + nt * 16 + c15] = f2b(acc[nt][r]);
    }
    float ps = 0.f, pd = 0.f;
#pragma unroll
    for (int nt = 0; nt < 4; nt++) {
      ps = fmaf(acc[nt][r], as4[nt], ps);
      pd = fmaf(acc[nt][r], ad4[nt], pd);
    }
#pragma unroll
    for (int o = 1; o < 16; o <<= 1) {
      ps += __shfl_xor(ps, o, 64);
      pd += __shfl_xor(pd, o, 64);
    }
    if (ok && c15 == 0) {
      sv[(size_t)p * n + row_g] = ps;
      dv[(size_t)p * n + row_g] = pd;
    }
  }
}

__device__ __forceinline__ void bin_role(
    u32* smem, int bf, EdgePtrs ep, u32* __restrict__ gcnt, u32* __restrict__ bbuf,
    int E, int nb) {
  int set = bf & 7, chunk = bf >> 3;
  const int* e = ep.e[set];
  u32* hist = smem;            // 256
  u32* gbase = smem + 256;     // 256
  u32* curs = smem + 512;      // 256
  u32* loffs = smem + 768;     // 257
  u32* sorted = smem + 1028;   // 4096
  int tid = threadIdx.x, lane = tid & 63, wv = tid >> 6;
  hist[tid] = 0;
  curs[tid] = 0;
  __syncthreads();
  int start = chunk * 4096;
  u32 pk_r[16];
#pragma unroll
  for (int t = 0; t < 16; t++) {
    int i = start + t * 256 + tid;
    u32 pk = 0xffffffffu;  // sentinel (real pk < 0xC350xxxx since d < n < 65536)
    if (i < E) {
      int s = e[i], d = e[E + i];
      if (s != d) {  // self-edges masked by ref -> weight 0
        pk = ((u32)d << 16) | (u32)s;
        atomicAdd(&hist[d >> 8], 1u);
      }
    }
    pk_r[t] = pk;
  }
  __syncthreads();
  if (hist[tid] > 0) gbase[tid] = atomicAdd(&gcnt[set * nb + tid], hist[tid]);
  if (wv == 0) {
    u32 carry = 0;
    for (int base = 0; base < 256; base += 64) {
      u32 v = hist[base + lane], x = v;
#pragma unroll
      for (int o = 1; o < 64; o <<= 1) { u32 y = __shfl_up(x, o, 64); if (lane >= o) x += y; }
      loffs[base + lane] = carry + x - v;
      carry += __shfl(x, 63, 64);
    }
    if (lane == 0) loffs[256] = carry;
  }
  __syncthreads();
#pragma unroll
  for (int t = 0; t < 16; t++) {
    u32 pk = pk_r[t];
    if (pk != 0xffffffffu) {
      int b = pk >> 24;  // (d << 16) >> 24 == d >> 8
      u32 pos = loffs[b] + atomicAdd(&curs[b], 1u);
      sorted[pos] = pk;
    }
  }
  __syncthreads();
  int cnt = (int)loffs[256];
  for (int j = tid; j < cnt; j += 256) {
    u32 pk = sorted[j];
    int b = pk >> 24;
    u32 gpos = gbase[b] + ((u32)j - loffs[b]);
    if (gpos >= CAP) gpos = CAP - 1;  // statistically impossible; memory safety only
    bbuf[((size_t)(set * nb + b)) * CAP + gpos] = pk;
  }
}

__global__ __launch_bounds__(256) void prep_kernel(
    EdgePtrs ep, u32* __restrict__ gcnt, u32* __restrict__ bbuf, int E, int nb,
    int nbin,
    const float* __restrict__ x, const float* __restrict__ W,
    const float* __restrict__ a_src, const float* __restrict__ a_dst,
    u16* __restrict__ H, float* __restrict__ sv, float* __restrict__ dv, int n) {
  __shared__ __align__(16) u32 smem[5248];  // 21 KB union: bin 20.5 KB / gemm 18.4 KB
  int f = blockIdx.x;
  if (f < nbin) bin_role(smem, f, ep, gcnt, bbuf, E, nb);
  else gemm_role(smem, f - nbin, x, W, a_src, a_dst, H, sv, dv, n);
}

// ---------------- kernel 3: per-bucket LDS counting-sort + aggregation.
// Grid = ntask/2 (multiple of 8), each block grid-strides over exactly 2 bucket
// tasks. All blocks co-resident from t=0 (784 blocks vs 1024 slots) -> no second
// scheduling round at 53% fill, no ragged multi-round drain (R3's 49.6% occupancy).
// task & 7 == blockIdx & 7 stays fixed -> set-to-XCD affinity preserved so each
// XCD's L2 keeps (mostly) one 6.4MB H panel.
__global__ __launch_bounds__(512) void agg_kernel(
    const u32* __restrict__ gcnt, const u32* __restrict__ bbuf,
    const u16* __restrict__ H, const float* __restrict__ sv,
    const float* __restrict__ dv, const float* __restrict__ bias,
    float* __restrict__ out, int n, int nb) {
  // input set order: tp_a,tp_b,tn_a,tn_b,dp_a,dp_b,dn_a,dn_b
  // output order:    tp_a,tp_b,dp_a,dp_b,tn_a,tn_b,dn_a,dn_b
  const int omap[8] = {0, 1, 4, 5, 2, 3, 6, 7};
  const int tid = threadIdx.x, lane = tid & 63, wv = tid >> 6;
  __shared__ u16 ss[CAP];        // 10 KB: src ids sorted by dst
  __shared__ float spe[CAP];     // 20 KB: exp-scores sorted by dst
  __shared__ u32 hist[256], offs[257], curs[256];
  __shared__ float dpw[256], spw[256];
  const int ntask = 8 * nb;
  for (int task = blockIdx.x; task < ntask; task += gridDim.x) {
    int set = task & 7, b = task >> 3, p = set >> 1;
    int node0 = b << 8;
    int nn = min(256, n - node0);
    const float* sp = sv + (size_t)p * n;
    const float* dp = dv + (size_t)p * n;
    for (int i = tid; i < 256; i += 512) { hist[i] = 0; curs[i] = 0; }
    for (int i = tid; i < nn; i += 512) { dpw[i] = dp[node0 + i]; spw[i] = sp[node0 + i]; }
    __syncthreads();
    int cnt = (int)gcnt[set * nb + b];
    if (cnt > CAP) cnt = CAP;
    const u32* eb = bbuf + ((size_t)(set * nb + b)) * CAP;
    // phase 1: single pass — load packed edges to registers, histogram, exp-scores.
    // CAP/512 == 10 -> fixed trip count, fully unrolled, static register indices.
    u32 pk_r[10];
    float pe_r[10];
#pragma unroll
    for (int t = 0; t < 10; t++) {
      int j = t * 512 + tid;
      u32 pk = 0;
      float pe = 0.f;
      if (j < cnt) {
        pk = eb[j];
        int s = pk & 0xffff, dl = (pk >> 16) & 255;
        atomicAdd(&hist[dl], 1u);
        pe = __expf(lrelu(sp[s] + dpw[dl]));
      }
      pk_r[t] = pk;
      pe_r[t] = pe;
    }
    __syncthreads();
    // phase 2: exclusive prefix scan (wave 0)
    if (wv == 0) {
      u32 carry = 0;
      for (int base = 0; base < 256; base += 64) {
        u32 v = hist[base + lane];
        u32 x = v;
#pragma unroll
        for (int o = 1; o < 64; o <<= 1) { u32 y = __shfl_up(x, o, 64); if (lane >= o) x += y; }
        offs[base + lane] = carry + x - v;
        carry += __shfl(x, 63, 64);
      }
      if (lane == 0) offs[256] = carry;
    }
    __syncthreads();
    // phase 3: pure LDS scatter into sorted order
#pragma unroll
    for (int t = 0; t < 10; t++) {
      int j = t * 512 + tid;
      if (j < cnt) {
        u32 pk = pk_r[t];
        int dl = (pk >> 16) & 255;
        u32 pos = offs[dl] + atomicAdd(&curs[dl], 1u);
        ss[pos] = (u16)(pk & 0xffff);
        spe[pos] = pe_r[t];
      }
    }
    __syncthreads();
    // phase 4: group g = lane>>3 owns one node; sub = lane&7 owns feats sub*8..+7.
    const u16* Hp = H + (size_t)p * n * 64;
    const int g = lane >> 3, sub = lane & 7;
    float4v bv0 = *(const float4v*)&bias[p * 64 + sub * 8];
    float4v bv1 = *(const float4v*)&bias[p * 64 + sub * 8 + 4];
    float* op = out + (size_t)omap[set] * n * 64;
    for (int r0 = 0; r0 < nn; r0 += 64) {
      int i = r0 + wv * 8 + g;          // this group's node (bucket-local)
      bool valid = i < nn;
      int iv = valid ? i : 0;
      int beg = (int)offs[iv], end2 = (int)offs[iv + 1];
      int cntg = valid ? (end2 - beg) : 0;
      int node = node0 + iv;
      // self-loop seeds the accumulators (its loads overlap the shfl-max below)
      float pself = valid ? __expf(lrelu(spw[iv] + dpw[iv])) : 0.f;
      uint4 hs = *(const uint4*)(Hp + ((size_t)node << 6) + (sub << 3));
      float den = pself;
      float a0 = pself * blo(hs.x), a1 = pself * bhi(hs.x);
      float a2 = pself * blo(hs.y), a3 = pself * bhi(hs.y);
      float a4 = pself * blo(hs.z), a5 = pself * bhi(hs.z);
      float a6 = pself * blo(hs.w), a7 = pself * bhi(hs.w);
      // wave-uniform trip count = max edge count over the wave's 8 groups
      int tmax = cntg;
#pragma unroll
      for (int o = 8; o < 64; o <<= 1) tmax = max(tmax, __shfl_xor(tmax, o, 64));
      // 4 edges per group per iteration: four independent gathers in flight.
      // Inactive slots clamp to j=0 (wave-uniform line -> cheap) with pe=0.
      for (int t = 0; t < tmax; t += 4) {
        bool c0 = t < cntg, c1 = t + 1 < cntg, c2 = t + 2 < cntg, c3 = t + 3 < cntg;
        int j0 = c0 ? beg + t : 0;
        int j1 = c1 ? beg + t + 1 : 0;
        int j2 = c2 ? beg + t + 2 : 0;
        int j3 = c3 ? beg + t + 3 : 0;
        float pe0 = c0 ? spe[j0] : 0.f;
        float pe1 = c1 ? spe[j1] : 0.f;
        float pe2 = c2 ? spe[j2] : 0.f;
        float pe3 = c3 ? spe[j3] : 0.f;
        int s0 = ss[j0], s1 = ss[j1], s2 = ss[j2], s3 = ss[j3];
        uint4 hv0 = *(const uint4*)(Hp + ((size_t)s0 << 6) + (sub << 3));
        uint4 hv1 = *(const uint4*)(Hp + ((size_t)s1 << 6) + (sub << 3));
        uint4 hv2 = *(const uint4*)(Hp + ((size_t)s2 << 6) + (sub << 3));
        uint4 hv3 = *(const uint4*)(Hp + ((size_t)s3 << 6) + (sub << 3));
        a0 = fmaf(pe0, blo(hv0.x), a0); a1 = fmaf(pe0, bhi(hv0.x), a1);
        a2 = fmaf(pe0, blo(hv0.y), a2); a3 = fmaf(pe0, bhi(hv0.y), a3);
        a4 = fmaf(pe0, blo(hv0.z), a4); a5 = fmaf(pe0, bhi(hv0.z), a5);
        a6 = fmaf(pe0, blo(hv0.w), a6); a7 = fmaf(pe0, bhi(hv0.w), a7);
        a0 = fmaf(pe1, blo(hv1.x), a0); a1 = fmaf(pe1, bhi(hv1.x), a1);
        a2 = fmaf(pe1, blo(hv1.y), a2); a3 = fmaf(pe1, bhi(hv1.y), a3);
        a4 = fmaf(pe1, blo(hv1.z), a4); a5 = fmaf(pe1, bhi(hv1.z), a5);
        a6 = fmaf(pe1, blo(hv1.w), a6); a7 = fmaf(pe1, bhi(hv1.w), a7);
        a0 = fmaf(pe2, blo(hv2.x), a0); a1 = fmaf(pe2, bhi(hv2.x), a1);
        a2 = fmaf(pe2, blo(hv2.y), a2); a3 = fmaf(pe2, bhi(hv2.y), a3);
        a4 = fmaf(pe2, blo(hv2.z), a4); a5 = fmaf(pe2, bhi(hv2.z), a5);
        a6 = fmaf(pe2, blo(hv2.w), a6); a7 = fmaf(pe2, bhi(hv2.w), a7);
        a0 = fmaf(pe3, blo(hv3.x), a0); a1 = fmaf(pe3, bhi(hv3.x), a1);
        a2 = fmaf(pe3, blo(hv3.y), a2); a3 = fmaf(pe3, bhi(hv3.y), a3);
        a4 = fmaf(pe3, blo(hv3.z), a4); a5 = fmaf(pe3, bhi(hv3.z), a5);
        a6 = fmaf(pe3, blo(hv3.w), a6); a7 = fmaf(pe3, bhi(hv3.w), a7);
        den += (pe0 + pe1) + (pe2 + pe3);
      }
      if (valid) {  // all 64 lanes store: 8 nodes x 256B contiguous per round
        float rd = 1.f / den;
        float4v o0 = {fmaxf(fmaf(a0, rd, bv0.x), 0.f), fmaxf(fmaf(a1, rd, bv0.y), 0.f),
                      fmaxf(fmaf(a2, rd, bv0.z), 0.f), fmaxf(fmaf(a3, rd, bv0.w), 0.f)};
        float4v o1 = {fmaxf(fmaf(a4, rd, bv1.x), 0.f), fmaxf(fmaf(a5, rd, bv1.y), 0.f),
                      fmaxf(fmaf(a6, rd, bv1.z), 0.f), fmaxf(fmaf(a7, rd, bv1.w), 0.f)};
        *(float4v*)&op[((size_t)node << 6) + (sub << 3)] = o0;
        *(float4v*)&op[((size_t)node << 6) + (sub << 3) + 4] = o1;
      }
    }
    __syncthreads();  // protect LDS (ss/spe/offs/dpw/spw) before next task reuses it
  }
}

extern "C" void kernel_launch(void* const* d_in, const int* in_sizes, int n_in,
                              void* d_out, int out_size, void* d_ws, size_t ws_size,
                              hipStream_t stream) {
  const int E = in_sizes[0] / 2;
  const int n = in_sizes[8] / 64;
  const int nb = (n + 255) >> 8;
  const float* x = (const float*)d_in[8];
  const float* W = (const float*)d_in[9];
  const float* a_src = (const float*)d_in[10];
  const float* a_dst = (const float*)d_in[11];
  const float* bias = (const float*)d_in[12];
  float* out = (float*)d_out;

  char* ws = (char*)d_ws;
  auto alloc = [&](size_t bytes) {
    char* p = ws;
    ws += (bytes + 255) & ~(size_t)255;
    return p;
  };
  u16* H = (u16*)alloc((size_t)4 * n * 64 * 2);
  float* sv = (float*)alloc((size_t)4 * n * 4);
  float* dv = (float*)alloc((size_t)4 * n * 4);
  u32* gcnt = (u32*)alloc((size_t)8 * nb * 4);
  u32* bbuf = (u32*)alloc((size_t)8 * nb * CAP * 4);

  EdgePtrs ep;
  for (int i = 0; i < 8; i++) ep.e[i] = (const int*)d_in[i];

  const int ebpb = (E + 4095) / 4096;      // edge chunks per set
  const int nbin = 8 * ebpb;               // bin blocks (first in flat grid)
  const int ngemm = ((n + 63) / 64) * 4;   // gemm blocks

  // agg grid: half the task count, rounded to a multiple of 8 (set affinity);
  // each block grid-strides over exactly ~2 tasks, all blocks co-resident.
  const int ntask = 8 * nb;
  int agrid = (ntask + 1) / 2;
  agrid = (agrid + 7) & ~7;
  if (agrid < 8) agrid = 8;

  dim3 b256(256);
  CSGDN_32031866093637_kernel<<<(8 * nb + 255) / 256, b256, 0, stream>>>(gcnt, 8 * nb);
  prep_kernel<<<nbin + ngemm, b256, 0, stream>>>(ep, gcnt, bbuf, E, nb, nbin,
                                                 x, W, a_src, a_dst, H, sv, dv, n);
  agg_kernel<<<agrid, dim3(512), 0, stream>>>(gcnt, bbuf, H, sv, dv, bias, out, n, nb);
}

// Round 6
// 289.484 us; speedup vs baseline: 1.6978x; 1.0830x over previous
//
#include <hip/hip_runtime.h>
#include <hip/hip_bf16.h>

typedef unsigned int u32;
typedef unsigned short u16;
typedef __hip_bfloat16 bf16;

typedef __attribute__((ext_vector_type(8))) short short8;
typedef __attribute__((ext_vector_type(4))) float float4v;

// 128-node dst buckets: mean edges/bucket = 800000/391 = 2046, sigma ~45 -> +17 sigma
#define CAP 2816

__device__ __forceinline__ float lrelu(float v) { return v > 0.f ? v : 0.2f * v; }

// f32 -> bf16 bits, round-to-nearest-even
__device__ __forceinline__ u16 f2b(float f) {
  u32 x = __float_as_uint(f);
  u32 r = (x + 0x7fffu + ((x >> 16) & 1u)) >> 16;
  return (u16)r;
}
__device__ __forceinline__ float b2fbits(u16 b) {
  return __uint_as_float(((u32)b) << 16);
}
// unpack a dword holding 2 bf16: low half = even feature, high half = odd feature
__device__ __forceinline__ float blo(u32 v) { return __uint_as_float(v << 16); }
__device__ __forceinline__ float bhi(u32 v) { return __uint_as_float(v & 0xffff0000u); }

struct EdgePtrs { const int* e[8]; };

// ---------------- kernel 0: zero bucket counters (graph-capture-safe memset)
__global__ __launch_bounds__(256) void CSGDN_32031866093637_kernel(u32* __restrict__ p,
                                                                   int count) {
  int i = blockIdx.x * 256 + threadIdx.x;
  if (i < count) p[i] = 0;
}

// ---------------- fused prep kernel: bin blocks first, then gemm blocks.
// bin and gemm are data-independent (bin: edges->bbuf/gcnt; gemm: x,W->H,sv,dv),
// so one dispatch lets memory-heavy bin overlap with compute-heavy gemm.

__device__ __forceinline__ void gemm_role(
    u32* smem, int g, const float* __restrict__ x, const float* __restrict__ W,
    const float* __restrict__ a_src, const float* __restrict__ a_dst,
    u16* __restrict__ H, float* __restrict__ sv, float* __restrict__ dv, int n) {
  const int p = g & 3;
  const int rowbase = (g >> 2) * 64;
  const int tid = threadIdx.x, lane = tid & 63, wv = tid >> 6;
  // padded stride 72 elem (144 B = 9*16B): b128-aligned, frag reads 2-way alias only
  short* xl = (short*)smem;          // 64*72 shorts = 9216 B
  short* wl = xl + 64 * 72;          // 64*72 shorts = 9216 B
#pragma unroll
  for (int it = 0; it < 16; it++) {
    int idx = it * 256 + tid;
    int r = idx >> 6, c = idx & 63;
    int gr = rowbase + r; if (gr > n - 1) gr = n - 1;
    xl[r * 72 + c] = (short)f2b(x[(size_t)gr * 64 + c]);
  }
#pragma unroll
  for (int it = 0; it < 16; it++) {
    int idx = it * 256 + tid;
    int k = idx >> 6, nc = idx & 63;
    wl[nc * 72 + k] = (short)f2b(W[p * 4096 + k * 64 + nc]);
  }
  __syncthreads();

  const int q = lane >> 4, c15 = lane & 15;
  const int wrow0 = wv * 16;  // this wave's 16 rows (local)
  short8 af0 = *(const short8*)&xl[(wrow0 + c15) * 72 + 0 * 32 + q * 8];
  short8 af1 = *(const short8*)&xl[(wrow0 + c15) * 72 + 1 * 32 + q * 8];
  float4v acc[4];
#pragma unroll
  for (int nt = 0; nt < 4; nt++) {
    acc[nt] = (float4v){0.f, 0.f, 0.f, 0.f};
    short8 b0 = *(const short8*)&wl[(nt * 16 + c15) * 72 + 0 * 32 + q * 8];
    short8 b1 = *(const short8*)&wl[(nt * 16 + c15) * 72 + 1 * 32 + q * 8];
    acc[nt] = __builtin_amdgcn_mfma_f32_16x16x32_bf16(af0, b0, acc[nt], 0, 0, 0);
    acc[nt] = __builtin_amdgcn_mfma_f32_16x16x32_bf16(af1, b1, acc[nt], 0, 0, 0);
  }
  // D layout: row = q*4 + r, col = nt*16 + c15
  u16* Hb = H + (size_t)p * n * 64;
  float as4[4], ad4[4];
#pragma unroll
  for (int nt = 0; nt < 4; nt++) {
    as4[nt] = a_src[p * 64 + nt * 16 + c15];
    ad4[nt] = a_dst[p * 64 + nt * 16 + c15];
  }
#pragma unroll
  for (int r = 0; r < 4; r++) {
    int row_g = rowbase + wrow0 + q * 4 + r;
    bool ok = row_g < n;
#pragma unroll
    for (int nt = 0; nt < 4; nt++) {
      if (ok) Hb[(size_t)row_g * 64 + nt * 16 + c15] = f2b(acc[nt][r]);
    }
    float ps = 0.f, pd = 0.f;
#pragma unroll
    for (int nt = 0; nt < 4; nt++) {
      ps = fmaf(acc[nt][r], as4[nt], ps);
      pd = fmaf(acc[nt][r], ad4[nt], pd);
    }
#pragma unroll
    for (int o = 1; o < 16; o <<= 1) {
      ps += __shfl_xor(ps, o, 64);
      pd += __shfl_xor(pd, o, 64);
    }
    if (ok && c15 == 0) {
      sv[(size_t)p * n + row_g] = ps;
      dv[(size_t)p * n + row_g] = pd;
    }
  }
}

// bin into 128-node buckets. nb <= 392 assumed (n <= 50176).
__device__ __forceinline__ void bin_role(
    u32* smem, int bf, EdgePtrs ep, u32* __restrict__ gcnt, u32* __restrict__ bbuf,
    int E, int nb) {
  int set = bf & 7, chunk = bf >> 3;
  const int* e = ep.e[set];
  u32* hist = smem;            // 392
  u32* gbase = smem + 392;     // 392
  u32* curs = smem + 784;      // 392
  u32* loffs = smem + 1176;    // 393
  u32* sorted = smem + 1572;   // 4096
  int tid = threadIdx.x, lane = tid & 63, wv = tid >> 6;
  for (int i = tid; i < nb; i += 256) { hist[i] = 0; curs[i] = 0; }
  __syncthreads();
  int start = chunk * 4096;
  u32 pk_r[16];
#pragma unroll
  for (int t = 0; t < 16; t++) {
    int i = start + t * 256 + tid;
    u32 pk = 0xffffffffu;  // sentinel (real pk has d < n < 65536)
    if (i < E) {
      int s = e[i], d = e[E + i];
      if (s != d) {  // self-edges masked by ref -> weight 0
        pk = ((u32)d << 16) | (u32)s;
        atomicAdd(&hist[d >> 7], 1u);
      }
    }
    pk_r[t] = pk;
  }
  __syncthreads();
  for (int i = tid; i < nb; i += 256)
    if (hist[i] > 0) gbase[i] = atomicAdd(&gcnt[set * nb + i], hist[i]);
  // exclusive prefix scan of hist over nb entries (wave 0)
  if (wv == 0) {
    u32 carry = 0;
    for (int base = 0; base < nb; base += 64) {
      u32 v = (base + lane < nb) ? hist[base + lane] : 0;
      u32 x = v;
#pragma unroll
      for (int o = 1; o < 64; o <<= 1) { u32 y = __shfl_up(x, o, 64); if (lane >= o) x += y; }
      if (base + lane < nb) loffs[base + lane] = carry + x - v;
      carry += __shfl(x, 63, 64);
    }
    if (lane == 0) loffs[nb] = carry;
  }
  __syncthreads();
#pragma unroll
  for (int t = 0; t < 16; t++) {
    u32 pk = pk_r[t];
    if (pk != 0xffffffffu) {
      int b = pk >> 23;  // (pk>>16) = d; d >> 7
      u32 pos = loffs[b] + atomicAdd(&curs[b], 1u);
      sorted[pos] = pk;
    }
  }
  __syncthreads();
  int cnt = (int)loffs[nb];
  // copy out: within each bucket run, consecutive j -> consecutive global slots
  for (int j = tid; j < cnt; j += 256) {
    u32 pk = sorted[j];
    int b = pk >> 23;
    u32 gpos = gbase[b] + ((u32)j - loffs[b]);
    if (gpos >= CAP) gpos = CAP - 1;  // statistically impossible; memory safety only
    bbuf[((size_t)(set * nb + b)) * CAP + gpos] = pk;
  }
}

__global__ __launch_bounds__(256) void prep_kernel(
    EdgePtrs ep, u32* __restrict__ gcnt, u32* __restrict__ bbuf, int E, int nb,
    int nbin,
    const float* __restrict__ x, const float* __restrict__ W,
    const float* __restrict__ a_src, const float* __restrict__ a_dst,
    u16* __restrict__ H, float* __restrict__ sv, float* __restrict__ dv, int n) {
  __shared__ __align__(16) u32 smem[5668];  // 22.7 KB union: bin 22.7 / gemm 18.4 KB
  int f = blockIdx.x;
  if (f < nbin) bin_role(smem, f, ep, gcnt, bbuf, E, nb);
  else gemm_role(smem, f - nbin, x, W, a_src, a_dst, H, sv, dv, n);
}

// ---------------- kernel 3: per-bucket LDS counting-sort + aggregation.
// 128-node buckets (halved): per-task tau ~29us (vs 58), 3128 tasks over ~1024
// resident slots -> finer-grained HW backfill, drain tail fraction halves.
// One task per block; HW dispatcher is the dynamic work queue (R4/R5 lesson:
// don't fight it with static striding or under-capacity grids).
// set = blockIdx&7 -> set-to-XCD affinity: each XCD's L2 holds mostly one H panel.
__global__ __launch_bounds__(512) void agg_kernel(
    const u32* __restrict__ gcnt, const u32* __restrict__ bbuf,
    const u16* __restrict__ H, const float* __restrict__ sv,
    const float* __restrict__ dv, const float* __restrict__ bias,
    float* __restrict__ out, int n, int nb) {
  // input set order: tp_a,tp_b,tn_a,tn_b,dp_a,dp_b,dn_a,dn_b
  // output order:    tp_a,tp_b,dp_a,dp_b,tn_a,tn_b,dn_a,dn_b
  const int omap[8] = {0, 1, 4, 5, 2, 3, 6, 7};
  int f = blockIdx.x;
  int set = f & 7, b = f >> 3, p = set >> 1;
  int tid = threadIdx.x, lane = tid & 63, wv = tid >> 6;
  int node0 = b << 7;
  int nn = min(128, n - node0);
  __shared__ u16 ss[CAP];        // 5.6 KB: src ids sorted by dst
  __shared__ float spe[CAP];     // 11.3 KB: exp-scores sorted by dst
  __shared__ u32 hist[128], offs[129], curs[128];
  __shared__ float dpw[128], spw[128];
  const float* sp = sv + (size_t)p * n;
  const float* dp = dv + (size_t)p * n;
  if (tid < 128) { hist[tid] = 0; curs[tid] = 0; }
  if (tid < nn) { dpw[tid] = dp[node0 + tid]; spw[tid] = sp[node0 + tid]; }
  __syncthreads();
  int cnt = (int)gcnt[set * nb + b];
  if (cnt > CAP) cnt = CAP;
  const u32* eb = bbuf + ((size_t)(set * nb + b)) * CAP;
  // phase 1: single pass — load packed edges to registers, histogram, exp-scores.
  // ceil(CAP/512) == 6 -> fixed trip count, fully unrolled, static register indices.
  u32 pk_r[6];
  float pe_r[6];
#pragma unroll
  for (int t = 0; t < 6; t++) {
    int j = t * 512 + tid;
    u32 pk = 0;
    float pe = 0.f;
    if (j < cnt) {
      pk = eb[j];
      int s = pk & 0xffff, dl = (pk >> 16) & 127;
      atomicAdd(&hist[dl], 1u);
      pe = __expf(lrelu(sp[s] + dpw[dl]));
    }
    pk_r[t] = pk;
    pe_r[t] = pe;
  }
  __syncthreads();
  // phase 2: exclusive prefix scan over 128 entries (wave 0)
  if (wv == 0) {
    u32 carry = 0;
#pragma unroll
    for (int base = 0; base < 128; base += 64) {
      u32 v = hist[base + lane];
      u32 x = v;
#pragma unroll
      for (int o = 1; o < 64; o <<= 1) { u32 y = __shfl_up(x, o, 64); if (lane >= o) x += y; }
      offs[base + lane] = carry + x - v;
      carry += __shfl(x, 63, 64);
    }
    if (lane == 0) offs[128] = carry;
  }
  __syncthreads();
  // phase 3: pure LDS scatter into sorted order
#pragma unroll
  for (int t = 0; t < 6; t++) {
    int j = t * 512 + tid;
    if (j < cnt) {
      u32 pk = pk_r[t];
      int dl = (pk >> 16) & 127;
      u32 pos = offs[dl] + atomicAdd(&curs[dl], 1u);
      ss[pos] = (u16)(pk & 0xffff);
      spe[pos] = pe_r[t];
    }
  }
  __syncthreads();
  // phase 4: group g = lane>>3 owns one node; sub = lane&7 owns feats sub*8..+7.
  const u16* Hp = H + (size_t)p * n * 64;
  const int g = lane >> 3, sub = lane & 7;
  float4v bv0 = *(const float4v*)&bias[p * 64 + sub * 8];
  float4v bv1 = *(const float4v*)&bias[p * 64 + sub * 8 + 4];
  float* op = out + (size_t)omap[set] * n * 64;
  for (int r0 = 0; r0 < nn; r0 += 64) {
    int i = r0 + wv * 8 + g;          // this group's node (bucket-local)
    bool valid = i < nn;
    int iv = valid ? i : 0;
    int beg = (int)offs[iv], end2 = (int)offs[iv + 1];
    int cntg = valid ? (end2 - beg) : 0;
    int node = node0 + iv;
    // self-loop seeds the accumulators (its loads overlap the shfl-max below)
    float pself = valid ? __expf(lrelu(spw[iv] + dpw[iv])) : 0.f;
    uint4 hs = *(const uint4*)(Hp + ((size_t)node << 6) + (sub << 3));
    float den = pself;
    float a0 = pself * blo(hs.x), a1 = pself * bhi(hs.x);
    float a2 = pself * blo(hs.y), a3 = pself * bhi(hs.y);
    float a4 = pself * blo(hs.z), a5 = pself * bhi(hs.z);
    float a6 = pself * blo(hs.w), a7 = pself * bhi(hs.w);
    // wave-uniform trip count = max edge count over the wave's 8 groups
    int tmax = cntg;
#pragma unroll
    for (int o = 8; o < 64; o <<= 1) tmax = max(tmax, __shfl_xor(tmax, o, 64));
    // 4 edges per group per iteration: four independent gathers in flight.
    // Inactive slots clamp to j=0 (wave-uniform line -> cheap) with pe=0.
    for (int t = 0; t < tmax; t += 4) {
      bool c0 = t < cntg, c1 = t + 1 < cntg, c2 = t + 2 < cntg, c3 = t + 3 < cntg;
      int j0 = c0 ? beg + t : 0;
      int j1 = c1 ? beg + t + 1 : 0;
      int j2 = c2 ? beg + t + 2 : 0;
      int j3 = c3 ? beg + t + 3 : 0;
      float pe0 = c0 ? spe[j0] : 0.f;
      float pe1 = c1 ? spe[j1] : 0.f;
      float pe2 = c2 ? spe[j2] : 0.f;
      float pe3 = c3 ? spe[j3] : 0.f;
      int s0 = ss[j0], s1 = ss[j1], s2 = ss[j2], s3 = ss[j3];
      uint4 hv0 = *(const uint4*)(Hp + ((size_t)s0 << 6) + (sub << 3));
      uint4 hv1 = *(const uint4*)(Hp + ((size_t)s1 << 6) + (sub << 3));
      uint4 hv2 = *(const uint4*)(Hp + ((size_t)s2 << 6) + (sub << 3));
      uint4 hv3 = *(const uint4*)(Hp + ((size_t)s3 << 6) + (sub << 3));
      a0 = fmaf(pe0, blo(hv0.x), a0); a1 = fmaf(pe0, bhi(hv0.x), a1);
      a2 = fmaf(pe0, blo(hv0.y), a2); a3 = fmaf(pe0, bhi(hv0.y), a3);
      a4 = fmaf(pe0, blo(hv0.z), a4); a5 = fmaf(pe0, bhi(hv0.z), a5);
      a6 = fmaf(pe0, blo(hv0.w), a6); a7 = fmaf(pe0, bhi(hv0.w), a7);
      a0 = fmaf(pe1, blo(hv1.x), a0); a1 = fmaf(pe1, bhi(hv1.x), a1);
      a2 = fmaf(pe1, blo(hv1.y), a2); a3 = fmaf(pe1, bhi(hv1.y), a3);
      a4 = fmaf(pe1, blo(hv1.z), a4); a5 = fmaf(pe1, bhi(hv1.z), a5);
      a6 = fmaf(pe1, blo(hv1.w), a6); a7 = fmaf(pe1, bhi(hv1.w), a7);
      a0 = fmaf(pe2, blo(hv2.x), a0); a1 = fmaf(pe2, bhi(hv2.x), a1);
      a2 = fmaf(pe2, blo(hv2.y), a2); a3 = fmaf(pe2, bhi(hv2.y), a3);
      a4 = fmaf(pe2, blo(hv2.z), a4); a5 = fmaf(pe2, bhi(hv2.z), a5);
      a6 = fmaf(pe2, blo(hv2.w), a6); a7 = fmaf(pe2, bhi(hv2.w), a7);
      a0 = fmaf(pe3, blo(hv3.x), a0); a1 = fmaf(pe3, bhi(hv3.x), a1);
      a2 = fmaf(pe3, blo(hv3.y), a2); a3 = fmaf(pe3, bhi(hv3.y), a3);
      a4 = fmaf(pe3, blo(hv3.z), a4); a5 = fmaf(pe3, bhi(hv3.z), a5);
      a6 = fmaf(pe3, blo(hv3.w), a6); a7 = fmaf(pe3, bhi(hv3.w), a7);
      den += (pe0 + pe1) + (pe2 + pe3);
    }
    if (valid) {  // all 64 lanes store: 8 nodes x 256B contiguous per round
      float rd = 1.f / den;
      float4v o0 = {fmaxf(fmaf(a0, rd, bv0.x), 0.f), fmaxf(fmaf(a1, rd, bv0.y), 0.f),
                    fmaxf(fmaf(a2, rd, bv0.z), 0.f), fmaxf(fmaf(a3, rd, bv0.w), 0.f)};
      float4v o1 = {fmaxf(fmaf(a4, rd, bv1.x), 0.f), fmaxf(fmaf(a5, rd, bv1.y), 0.f),
                    fmaxf(fmaf(a6, rd, bv1.z), 0.f), fmaxf(fmaf(a7, rd, bv1.w), 0.f)};
      *(float4v*)&op[((size_t)node << 6) + (sub << 3)] = o0;
      *(float4v*)&op[((size_t)node << 6) + (sub << 3) + 4] = o1;
    }
  }
}

extern "C" void kernel_launch(void* const* d_in, const int* in_sizes, int n_in,
                              void* d_out, int out_size, void* d_ws, size_t ws_size,
                              hipStream_t stream) {
  const int E = in_sizes[0] / 2;
  const int n = in_sizes[8] / 64;
  const int nb = (n + 127) >> 7;   // 128-node buckets
  const float* x = (const float*)d_in[8];
  const float* W = (const float*)d_in[9];
  const float* a_src = (const float*)d_in[10];
  const float* a_dst = (const float*)d_in[11];
  const float* bias = (const float*)d_in[12];
  float* out = (float*)d_out;

  char* ws = (char*)d_ws;
  auto alloc = [&](size_t bytes) {
    char* p = ws;
    ws += (bytes + 255) & ~(size_t)255;
    return p;
  };
  u16* H = (u16*)alloc((size_t)4 * n * 64 * 2);
  float* sv = (float*)alloc((size_t)4 * n * 4);
  float* dv = (float*)alloc((size_t)4 * n * 4);
  u32* gcnt = (u32*)alloc((size_t)8 * nb * 4);
  u32* bbuf = (u32*)alloc((size_t)8 * nb * CAP * 4);

  EdgePtrs ep;
  for (int i = 0; i < 8; i++) ep.e[i] = (const int*)d_in[i];

  const int ebpb = (E + 4095) / 4096;      // edge chunks per set
  const int nbin = 8 * ebpb;               // bin blocks (first in flat grid)
  const int ngemm = ((n + 63) / 64) * 4;   // gemm blocks

  dim3 b256(256);
  CSGDN_32031866093637_kernel<<<(8 * nb + 255) / 256, b256, 0, stream>>>(gcnt, 8 * nb);
  prep_kernel<<<nbin + ngemm, b256, 0, stream>>>(ep, gcnt, bbuf, E, nb, nbin,
                                                 x, W, a_src, a_dst, H, sv, dv, n);
  agg_kernel<<<nb * 8, dim3(512), 0, stream>>>(gcnt, bbuf, H, sv, dv, bias, out, n, nb);
}